// Round 2
// baseline (260.610 us; speedup 1.0000x reference)
//
#include <hip/hip_runtime.h>
#include <hip/hip_bf16.h>

// Problem constants
// B=64, N=256, IN=512, OUT=512, K_SLOTS=8, DK=64
// inputs: node_feats (64*256*512 f32), adj (64*8*256*256 f32), weight (512*512 f32), bias (512 f32)
// out: (64*256*512) f32

typedef __attribute__((ext_vector_type(8))) short short8;   // 8 bf16 (4 VGPRs) - MFMA A/B frag
typedef __attribute__((ext_vector_type(4))) float floatx4;  // MFMA C/D frag

__device__ __forceinline__ unsigned short f2bf(float f) {
    union { float f; unsigned u; } v; v.f = f;
    unsigned r = v.u + 0x7FFFu + ((v.u >> 16) & 1u);  // RNE
    return (unsigned short)(r >> 16);
}

// ---------------------------------------------------------------------------
// Pre-kernel: W (512x512, row-major [k][o]) -> Wt bf16 [o][k] (k contiguous)
// ---------------------------------------------------------------------------
__global__ __launch_bounds__(256) void wt_kernel(const float* __restrict__ W,
                                                 unsigned short* __restrict__ Wt) {
    int idx = blockIdx.x * 256 + threadIdx.x;  // 0..262143, coalesced read
    int k = idx >> 9;
    int o = idx & 511;
    Wt[o * 512 + k] = f2bf(W[idx]);
}

// ---------------------------------------------------------------------------
// Kernel 1: hT[((b*8+ks)*64+d)*256 + m] = bf16(relu(X@W + bias))
// grid (128, 4), block 256 (4 waves, each 64x64 output)
// ---------------------------------------------------------------------------
__global__ __launch_bounds__(256) void gemm_relu_kernel(
    const float* __restrict__ X, const unsigned short* __restrict__ Wt,
    const float* __restrict__ bias, unsigned short* __restrict__ hT) {
    // +8-short pad per 32-k row: row stride 40 shorts -> 2-way LDS conflicts (free)
    __shared__ unsigned short a_lds[128 * 40];
    __shared__ unsigned short b_lds[128 * 40];

    const int tid = threadIdx.x;
    const int lane = tid & 63, wid = tid >> 6;
    const int wm = (wid & 1) * 64, wn = (wid >> 1) * 64;
    const int lrow = lane & 15, quad = lane >> 4;
    const int m_base = blockIdx.x * 128;   // global M (b*256+m)
    const int o_base = blockIdx.y * 128;   // global N (o)

    floatx4 acc[4][4];
    const floatx4 fzero = {0.f, 0.f, 0.f, 0.f};
#pragma unroll
    for (int i = 0; i < 4; ++i)
#pragma unroll
        for (int j = 0; j < 4; ++j) acc[i][j] = fzero;

    for (int kb = 0; kb < 16; ++kb) {
        const int k0 = kb * 32;
        // stage A tile: X fp32 -> bf16, 128 rows x 32 k (1024 float4-chunks)
#pragma unroll
        for (int i = 0; i < 4; ++i) {
            int c4 = tid + i * 256;          // 0..1023
            int r = c4 >> 3;
            int cc = (c4 & 7) * 4;
            const float4 v = *(const float4*)(X + (size_t)(m_base + r) * 512 + k0 + cc);
            ushort4 p;
            p.x = f2bf(v.x); p.y = f2bf(v.y); p.z = f2bf(v.z); p.w = f2bf(v.w);
            *(ushort4*)(a_lds + r * 40 + cc) = p;
        }
        // stage B tile: Wt bf16 [o][k], 128 rows x 32 k (1024 ushort4-chunks)
        // (Round-0 bug: only 512 chunks staged -> k=16..31 was uninitialized LDS -> NaN)
#pragma unroll
        for (int i = 0; i < 4; ++i) {
            int c4 = tid + i * 256;          // 0..1023
            int r = c4 >> 3;
            int cc = (c4 & 7) * 4;
            *(ushort4*)(b_lds + r * 40 + cc) =
                *(const ushort4*)(Wt + (size_t)(o_base + r) * 512 + k0 + cc);
        }
        __syncthreads();

        short8 af[4], bfr[4];
#pragma unroll
        for (int i = 0; i < 4; ++i)
            af[i] = *(const short8*)(a_lds + (wm + 16 * i + lrow) * 40 + quad * 8);
#pragma unroll
        for (int j = 0; j < 4; ++j)
            bfr[j] = *(const short8*)(b_lds + (wn + 16 * j + lrow) * 40 + quad * 8);
#pragma unroll
        for (int i = 0; i < 4; ++i)
#pragma unroll
            for (int j = 0; j < 4; ++j)
                acc[i][j] = __builtin_amdgcn_mfma_f32_16x16x32_bf16(af[i], bfr[j], acc[i][j], 0, 0, 0);
        __syncthreads();
    }

    // epilogue: bias + relu + bf16, write transposed hT[d-row][m]
    const int b = blockIdx.x >> 1;
    const int m_in_b = (blockIdx.x & 1) * 128;
#pragma unroll
    for (int j = 0; j < 4; ++j) {
        int o = o_base + wn + 16 * j + lrow;  // C/D col = lane&15
        float bv = bias[o];
        int ks = o >> 6, d = o & 63;
        unsigned short* dst = hT + ((size_t)(b * 8 + ks) * 64 + d) * 256;
#pragma unroll
        for (int i = 0; i < 4; ++i) {
            int m = m_in_b + wm + 16 * i + quad * 4;  // C/D row = quad*4+reg
            floatx4 c = acc[i][j];
            ushort4 p;
            p.x = f2bf(fmaxf(c.x + bv, 0.f));
            p.y = f2bf(fmaxf(c.y + bv, 0.f));
            p.z = f2bf(fmaxf(c.z + bv, 0.f));
            p.w = f2bf(fmaxf(c.w + bv, 0.f));
            *(ushort4*)(dst + m) = p;  // 4 consecutive m -> 8B store
        }
    }
}

// ---------------------------------------------------------------------------
// Kernel 2: out[b,n,ks*64+d] = sum_m adj[b,ks,n,m] * hT[b,ks,d,m]
// grid 1024 (= (b*8+ks)*2 + half), block 256 (4 waves, each 32n x 64d)
// adj streamed global->reg->bf16 (read exactly once, no reuse -> no LDS)
// ---------------------------------------------------------------------------
__global__ __launch_bounds__(256) void agg_kernel(const float* __restrict__ adj,
                                                  const unsigned short* __restrict__ hT,
                                                  float* __restrict__ out) {
    const int tid = threadIdx.x;
    const int lane = tid & 63, wid = tid >> 6;
    const int bk = blockIdx.x >> 1;   // b*8+ks
    const int half = blockIdx.x & 1;
    const int b = bk >> 3, ks = bk & 7;
    const int lrow = lane & 15, quad = lane >> 4;
    const int n0 = half * 128 + wid * 32;

    const float* A = adj + (size_t)bk * 65536;          // [n][m] 256x256 f32
    const unsigned short* Bh = hT + (size_t)bk * 16384; // [d][m] 64x256 bf16

    floatx4 acc[2][4];
    const floatx4 fzero = {0.f, 0.f, 0.f, 0.f};
#pragma unroll
    for (int i = 0; i < 2; ++i)
#pragma unroll
        for (int j = 0; j < 4; ++j) acc[i][j] = fzero;

    for (int mt = 0; mt < 8; ++mt) {
        const int m0 = mt * 32 + quad * 8;  // A/B frag k-offset for this lane
        short8 af[2], bfr[4];
#pragma unroll
        for (int i = 0; i < 2; ++i) {
            const float* src = A + (size_t)(n0 + 16 * i + lrow) * 256 + m0;
            float4 v0 = *(const float4*)src;
            float4 v1 = *(const float4*)(src + 4);
            short8 t;
            t[0] = (short)f2bf(v0.x); t[1] = (short)f2bf(v0.y);
            t[2] = (short)f2bf(v0.z); t[3] = (short)f2bf(v0.w);
            t[4] = (short)f2bf(v1.x); t[5] = (short)f2bf(v1.y);
            t[6] = (short)f2bf(v1.z); t[7] = (short)f2bf(v1.w);
            af[i] = t;
        }
#pragma unroll
        for (int j = 0; j < 4; ++j)
            bfr[j] = *(const short8*)(Bh + (16 * j + lrow) * 256 + m0);  // 16B aligned
#pragma unroll
        for (int i = 0; i < 2; ++i)
#pragma unroll
            for (int j = 0; j < 4; ++j)
                acc[i][j] = __builtin_amdgcn_mfma_f32_16x16x32_bf16(af[i], bfr[j], acc[i][j], 0, 0, 0);
    }

    // epilogue: C/D layout col=lane&15 (d), row=quad*4+reg (n)
#pragma unroll
    for (int i = 0; i < 2; ++i) {
#pragma unroll
        for (int j = 0; j < 4; ++j) {
            int n = n0 + 16 * i + quad * 4;
            int d = 16 * j + lrow;
            float* dst = out + ((size_t)b * 256 + n) * 512 + ks * 64 + d;
            floatx4 c = acc[i][j];
            dst[0 * 512] = c.x;
            dst[1 * 512] = c.y;
            dst[2 * 512] = c.z;
            dst[3 * 512] = c.w;
        }
    }
}

// ---------------------------------------------------------------------------
extern "C" void kernel_launch(void* const* d_in, const int* in_sizes, int n_in,
                              void* d_out, int out_size, void* d_ws, size_t ws_size,
                              hipStream_t stream) {
    const float* X    = (const float*)d_in[0];  // node_feats
    const float* adj  = (const float*)d_in[1];  // adj
    const float* W    = (const float*)d_in[2];  // weight
    const float* bias = (const float*)d_in[3];  // bias
    float* out = (float*)d_out;

    // workspace layout: hT bf16 [64*8*64*256] (16 MiB), then Wt bf16 [512*512]
    unsigned short* hT = (unsigned short*)d_ws;
    unsigned short* Wt = hT + (size_t)64 * 8 * 64 * 256;

    wt_kernel<<<1024, 256, 0, stream>>>(W, Wt);
    gemm_relu_kernel<<<dim3(128, 4), 256, 0, stream>>>(X, Wt, bias, hT);
    agg_kernel<<<1024, 256, 0, stream>>>(adj, hT, out);
}

// Round 3
// 255.207 us; speedup vs baseline: 1.0212x; 1.0212x over previous
//
#include <hip/hip_runtime.h>
#include <hip/hip_bf16.h>

// Problem constants
// B=64, N=256, IN=512, OUT=512, K_SLOTS=8, DK=64
// inputs: node_feats (64*256*512 f32), adj (64*8*256*256 f32), weight (512*512 f32), bias (512 f32)
// out: (64*256*512) f32

typedef __attribute__((ext_vector_type(8))) short short8;   // 8 bf16 (4 VGPRs) - MFMA A/B frag
typedef __attribute__((ext_vector_type(4))) float floatx4;  // MFMA C/D frag

__device__ __forceinline__ unsigned short f2bf(float f) {
    union { float f; unsigned u; } v; v.f = f;
    unsigned r = v.u + 0x7FFFu + ((v.u >> 16) & 1u);  // RNE
    return (unsigned short)(r >> 16);
}

// packed f32x2 -> bf16x2 (RNE); compiles to v_cvt_pk_bf16_f32 on gfx950
__device__ __forceinline__ unsigned pk2bf(float a, float b) {
    union { __hip_bfloat162 h; unsigned u; } cv;
    cv.h = __float22bfloat162_rn(make_float2(a, b));
    return cv.u;
}

// ---------------------------------------------------------------------------
// Pre-kernel: W (512x512, row-major [k][o]) -> Wt bf16 [o][k] (k contiguous)
// LDS-tiled transpose, 64x64 tiles, coalesced read AND write.
// ---------------------------------------------------------------------------
__global__ __launch_bounds__(256) void wt_kernel(const float* __restrict__ W,
                                                 unsigned short* __restrict__ Wt) {
    __shared__ unsigned short t_lds[64 * 66];  // [o][k], pad 66 -> 2-way (free)
    const int tile = blockIdx.x;      // 0..63 (8x8 tiles)
    const int k0 = (tile >> 3) * 64;
    const int o0 = (tile & 7) * 64;
    const int t = threadIdx.x;
    const int c = t & 63;             // coalesced dim
    const int rb = t >> 6;            // 0..3
#pragma unroll
    for (int i = 0; i < 16; ++i) {
        int r = i * 4 + rb;           // k-row within tile
        t_lds[c * 66 + r] = f2bf(W[(size_t)(k0 + r) * 512 + o0 + c]);
    }
    __syncthreads();
#pragma unroll
    for (int i = 0; i < 16; ++i) {
        int o_r = i * 4 + rb;         // o-row within tile
        Wt[(size_t)(o0 + o_r) * 512 + k0 + c] = t_lds[o_r * 66 + c];
    }
}

// ---------------------------------------------------------------------------
// Kernel 1: hT[((b*8+ks)*64+d)*256 + m] = bf16(relu(X@W + bias))
// 1D grid 512, block 256 (4 waves, each 64x64 output).
// Swizzle: blocks sharing an X m-tile have ids == mod 8 -> same XCD L2,
// adjacent dispatch time -> X fetched from HBM once (~34MB, was 134MB).
// ---------------------------------------------------------------------------
__global__ __launch_bounds__(256) void gemm_relu_kernel(
    const float* __restrict__ X, const unsigned short* __restrict__ Wt,
    const float* __restrict__ bias, unsigned short* __restrict__ hT) {
    // +8-short pad per 32-k row: row stride 40 shorts -> 2-way LDS conflicts (free)
    __shared__ unsigned short a_lds[128 * 40];
    __shared__ unsigned short b_lds[128 * 40];

    const int id = blockIdx.x;        // 0..511
    const int r8 = id & 7;            // XCD residue
    const int yt = (id >> 3) & 3;     // o-tile
    const int q  = id >> 5;           // 0..15
    const int m_tile = r8 + 8 * q;    // 0..127
    const int m_base = m_tile * 128;  // global M (b*256+m)
    const int o_base = yt * 128;      // global N (o)

    const int tid = threadIdx.x;
    const int lane = tid & 63, wid = tid >> 6;
    const int wm = (wid & 1) * 64, wn = (wid >> 1) * 64;
    const int lrow = lane & 15, quad = lane >> 4;

    floatx4 acc[4][4];
    const floatx4 fzero = {0.f, 0.f, 0.f, 0.f};
#pragma unroll
    for (int i = 0; i < 4; ++i)
#pragma unroll
        for (int j = 0; j < 4; ++j) acc[i][j] = fzero;

    for (int kb = 0; kb < 16; ++kb) {
        const int k0 = kb * 32;
        // stage A tile: X fp32 -> bf16, 128 rows x 32 k (1024 float4-chunks)
#pragma unroll
        for (int i = 0; i < 4; ++i) {
            int c4 = tid + i * 256;          // 0..1023
            int rr = c4 >> 3;
            int cc = (c4 & 7) * 4;
            const float4 v = *(const float4*)(X + (size_t)(m_base + rr) * 512 + k0 + cc);
            unsigned p01 = pk2bf(v.x, v.y);
            unsigned p23 = pk2bf(v.z, v.w);
            unsigned* dst = (unsigned*)(a_lds + rr * 40 + cc);
            dst[0] = p01; dst[1] = p23;
        }
        // stage B tile: Wt bf16 [o][k], 128 rows x 32 k (1024 ushort4-chunks)
#pragma unroll
        for (int i = 0; i < 4; ++i) {
            int c4 = tid + i * 256;          // 0..1023
            int rr = c4 >> 3;
            int cc = (c4 & 7) * 4;
            *(ushort4*)(b_lds + rr * 40 + cc) =
                *(const ushort4*)(Wt + (size_t)(o_base + rr) * 512 + k0 + cc);
        }
        __syncthreads();

        short8 af[4], bfr[4];
#pragma unroll
        for (int i = 0; i < 4; ++i)
            af[i] = *(const short8*)(a_lds + (wm + 16 * i + lrow) * 40 + quad * 8);
#pragma unroll
        for (int j = 0; j < 4; ++j)
            bfr[j] = *(const short8*)(b_lds + (wn + 16 * j + lrow) * 40 + quad * 8);
#pragma unroll
        for (int i = 0; i < 4; ++i)
#pragma unroll
            for (int j = 0; j < 4; ++j)
                acc[i][j] = __builtin_amdgcn_mfma_f32_16x16x32_bf16(af[i], bfr[j], acc[i][j], 0, 0, 0);
        __syncthreads();
    }

    // epilogue: bias + relu + bf16, write transposed hT[d-row][m]
    const int b = m_tile >> 1;
    const int m_in_b = (m_tile & 1) * 128;
#pragma unroll
    for (int j = 0; j < 4; ++j) {
        int o = o_base + wn + 16 * j + lrow;  // C/D col = lane&15
        float bv = bias[o];
        int ks = o >> 6, d = o & 63;
        unsigned short* dst = hT + ((size_t)(b * 8 + ks) * 64 + d) * 256;
#pragma unroll
        for (int i = 0; i < 4; ++i) {
            int m = m_in_b + wm + 16 * i + quad * 4;  // C/D row = quad*4+reg
            floatx4 c = acc[i][j];
            unsigned p01 = pk2bf(fmaxf(c.x + bv, 0.f), fmaxf(c.y + bv, 0.f));
            unsigned p23 = pk2bf(fmaxf(c.z + bv, 0.f), fmaxf(c.w + bv, 0.f));
            unsigned* d32 = (unsigned*)(dst + m);
            d32[0] = p01; d32[1] = p23;   // 8B store, 4 consecutive m
        }
    }
}

// ---------------------------------------------------------------------------
// Kernel 2: out[b,n,ks*64+d] = sum_m adj[b,ks,n,m] * hT[b,ks,d,m]
// 1D grid 1024, block 256 (4 waves, each 32n x 64d).
// Swizzle: the 2 blocks sharing one hT slab have ids == mod 8 -> same XCD.
// adj streamed global->reg->bf16 (read exactly once, no reuse -> no LDS)
// ---------------------------------------------------------------------------
__global__ __launch_bounds__(256) void agg_kernel(const float* __restrict__ adj,
                                                  const unsigned short* __restrict__ hT,
                                                  float* __restrict__ out) {
    const int id = blockIdx.x;        // 0..1023
    const int r8 = id & 7;
    const int half = (id >> 3) & 1;
    const int q = id >> 4;            // 0..63
    const int bk = r8 + 8 * q;        // b*8+ks, 0..511

    const int tid = threadIdx.x;
    const int lane = tid & 63, wid = tid >> 6;
    const int b = bk >> 3, ks = bk & 7;
    const int lrow = lane & 15, quad = lane >> 4;
    const int n0 = half * 128 + wid * 32;

    const float* A = adj + (size_t)bk * 65536;          // [n][m] 256x256 f32
    const unsigned short* Bh = hT + (size_t)bk * 16384; // [d][m] 64x256 bf16

    floatx4 acc[2][4];
    const floatx4 fzero = {0.f, 0.f, 0.f, 0.f};
#pragma unroll
    for (int i = 0; i < 2; ++i)
#pragma unroll
        for (int j = 0; j < 4; ++j) acc[i][j] = fzero;

    for (int mt = 0; mt < 8; ++mt) {
        const int m0 = mt * 32 + quad * 8;  // A/B frag k-offset for this lane
        short8 af[2], bfr[4];
#pragma unroll
        for (int i = 0; i < 2; ++i) {
            const float* src = A + (size_t)(n0 + 16 * i + lrow) * 256 + m0;
            float4 v0 = *(const float4*)src;
            float4 v1 = *(const float4*)(src + 4);
            union { short8 s; unsigned u[4]; } t;
            t.u[0] = pk2bf(v0.x, v0.y);
            t.u[1] = pk2bf(v0.z, v0.w);
            t.u[2] = pk2bf(v1.x, v1.y);
            t.u[3] = pk2bf(v1.z, v1.w);
            af[i] = t.s;
        }
#pragma unroll
        for (int j = 0; j < 4; ++j)
            bfr[j] = *(const short8*)(Bh + (16 * j + lrow) * 256 + m0);  // 16B aligned
#pragma unroll
        for (int i = 0; i < 2; ++i)
#pragma unroll
            for (int j = 0; j < 4; ++j)
                acc[i][j] = __builtin_amdgcn_mfma_f32_16x16x32_bf16(af[i], bfr[j], acc[i][j], 0, 0, 0);
    }

    // epilogue: C/D layout col=lane&15 (d), row=quad*4+reg (n)
#pragma unroll
    for (int i = 0; i < 2; ++i) {
#pragma unroll
        for (int j = 0; j < 4; ++j) {
            int n = n0 + 16 * i + quad * 4;
            int d = 16 * j + lrow;
            float* dst = out + ((size_t)b * 256 + n) * 512 + ks * 64 + d;
            floatx4 c = acc[i][j];
            dst[0 * 512] = c.x;
            dst[1 * 512] = c.y;
            dst[2 * 512] = c.z;
            dst[3 * 512] = c.w;
        }
    }
}

// ---------------------------------------------------------------------------
extern "C" void kernel_launch(void* const* d_in, const int* in_sizes, int n_in,
                              void* d_out, int out_size, void* d_ws, size_t ws_size,
                              hipStream_t stream) {
    const float* X    = (const float*)d_in[0];  // node_feats
    const float* adj  = (const float*)d_in[1];  // adj
    const float* W    = (const float*)d_in[2];  // weight
    const float* bias = (const float*)d_in[3];  // bias
    float* out = (float*)d_out;

    // workspace layout: hT bf16 [64*8*64*256] (16 MiB), then Wt bf16 [512*512]
    unsigned short* hT = (unsigned short*)d_ws;
    unsigned short* Wt = hT + (size_t)64 * 8 * 64 * 256;

    wt_kernel<<<64, 256, 0, stream>>>(W, Wt);
    gemm_relu_kernel<<<512, 256, 0, stream>>>(X, Wt, bias, hT);
    agg_kernel<<<1024, 256, 0, stream>>>(adj, hT, out);
}